// Round 1
// baseline (1790.303 us; speedup 1.0000x reference)
//
#include <hip/hip_runtime.h>
#include <hip/hip_bf16.h>

// LinearCEMTPLoss: logits = h @ W^T (and mtp), fused online-softmax CE/KL/argmax.
// B=2,S=2048 -> N=4096 tokens, D=2048, V=32000. Outputs: 5 fp32 scalars.

typedef __bf16 bf16x8 __attribute__((ext_vector_type(8)));
typedef float f32x4 __attribute__((ext_vector_type(4)));

#define D_DIM 2048
#define N_TOK 4096
#define V_DIM 32000
#define NVT 250   /* 32000/128 vocab tiles */
#define NMT 32    /* 4096/128 token tiles */

__device__ __forceinline__ void async_ld16(const void* g, void* l) {
  __builtin_amdgcn_global_load_lds(
      (const __attribute__((address_space(1))) unsigned int*)g,
      (__attribute__((address_space(3))) unsigned int*)l, 16, 0, 0);
}

// ---------------- fp32 -> bf16 convert (8 elems/thread) ----------------
__global__ void cvt_f32_bf16(const float* __restrict__ s, __bf16* __restrict__ d, long n8) {
  long i = (long)blockIdx.x * blockDim.x + threadIdx.x;
  if (i >= n8) return;
  const float4* s4 = (const float4*)s;
  float4 a = s4[2 * i], b = s4[2 * i + 1];
  bf16x8 o;
  o[0] = (__bf16)a.x; o[1] = (__bf16)a.y; o[2] = (__bf16)a.z; o[3] = (__bf16)a.w;
  o[4] = (__bf16)b.x; o[5] = (__bf16)b.y; o[6] = (__bf16)b.z; o[7] = (__bf16)b.w;
  *(bf16x8*)(d + i * 8) = o;
}

// ---------------- target-logit dot (fp32, 1 wave/token) ----------------
__global__ void tgt_dot(const float* __restrict__ h, const float* __restrict__ mtp,
                        const float* __restrict__ W, const int* __restrict__ tgt,
                        float* __restrict__ tl1, float* __restrict__ tl2) {
  int token = blockIdx.x * 4 + (threadIdx.x >> 6);
  int lane = threadIdx.x & 63;
  int g = tgt[token];
  int sg = g < 0 ? 0 : g;
  const float4* hr = (const float4*)(h + (long)token * D_DIM);
  const float4* mr = (const float4*)(mtp + (long)token * D_DIM);
  const float4* wr = (const float4*)(W + (long)sg * D_DIM);
  float s1 = 0.f, s2 = 0.f;
#pragma unroll
  for (int c = 0; c < 8; ++c) {
    int j = lane + c * 64;
    float4 w = wr[j], a = hr[j], b = mr[j];
    s1 += a.x * w.x + a.y * w.y + a.z * w.z + a.w * w.w;
    s2 += b.x * w.x + b.y * w.y + b.z * w.z + b.w * w.w;
  }
  for (int mask = 1; mask < 64; mask <<= 1) {
    s1 += __shfl_xor(s1, mask, 64);
    s2 += __shfl_xor(s2, mask, 64);
  }
  if (lane == 0) { tl1[token] = s1; tl2[token] = s2; }
}

// ---------------- fused dual GEMM + online softmax partials ----------------
// grid: (NMT token tiles, NVT vocab tiles); block 256 = 4 waves (2x2), wave=64x64.
__global__ __launch_bounds__(256, 2) void fused_gemm(
    const __bf16* __restrict__ A1, const __bf16* __restrict__ A2,
    const __bf16* __restrict__ Bw,
    float* __restrict__ pm1, float* __restrict__ pz1, float* __restrict__ pt,
    float* __restrict__ pi1, float* __restrict__ pm2, float* __restrict__ pz2,
    float* __restrict__ pi2) {
  __shared__ __align__(16) __bf16 sA1[128 * 64];
  __shared__ __align__(16) __bf16 sA2[128 * 64];
  __shared__ __align__(16) __bf16 sB[128 * 64];
  __shared__ float red[128 * 2 * 8];

  const int tid = threadIdx.x;
  const int wave = tid >> 6;
  const int lane = tid & 63;
  const int wm = wave & 1, wn = wave >> 1;
  const int quad = lane >> 4, l15 = lane & 15;

  const int m0 = blockIdx.x * 128;  // token tile base
  const int n0 = blockIdx.y * 128;  // vocab tile base

  // staging: wave w loads rows [w*32, w*32+32) of each tile; 8 rows/instr
  const int srow = wave * 32 + (lane >> 3);
  const int schunk = lane & 7;
  const __bf16* gA1 = A1 + (long)(m0 + srow) * D_DIM + schunk * 8;
  const __bf16* gA2 = A2 + (long)(m0 + srow) * D_DIM + schunk * 8;
  const __bf16* gB = Bw + (long)(n0 + srow) * D_DIM + schunk * 8;

  f32x4 acc1[4][4], acc2[4][4];
#pragma unroll
  for (int a = 0; a < 4; ++a)
#pragma unroll
    for (int b = 0; b < 4; ++b) {
      acc1[a][b] = (f32x4){0.f, 0.f, 0.f, 0.f};
      acc2[a][b] = (f32x4){0.f, 0.f, 0.f, 0.f};
    }

  for (int ks = 0; ks < D_DIM / 64; ++ks) {
    const int koff = ks * 64;
#pragma unroll
    for (int i = 0; i < 4; ++i) {
      async_ld16(gA1 + (long)i * 8 * D_DIM + koff, &sA1[(wave * 32 + i * 8) * 64]);
      async_ld16(gA2 + (long)i * 8 * D_DIM + koff, &sA2[(wave * 32 + i * 8) * 64]);
      async_ld16(gB + (long)i * 8 * D_DIM + koff, &sB[(wave * 32 + i * 8) * 64]);
    }
    __syncthreads();
#pragma unroll
    for (int kk = 0; kk < 2; ++kk) {
      bf16x8 af1[4], af2[4], bfr[4];
#pragma unroll
      for (int f = 0; f < 4; ++f) {
        af1[f] = *(const bf16x8*)&sA1[(wm * 64 + f * 16 + l15) * 64 + kk * 32 + quad * 8];
        af2[f] = *(const bf16x8*)&sA2[(wm * 64 + f * 16 + l15) * 64 + kk * 32 + quad * 8];
        bfr[f] = *(const bf16x8*)&sB[(wn * 64 + f * 16 + l15) * 64 + kk * 32 + quad * 8];
      }
#pragma unroll
      for (int fm = 0; fm < 4; ++fm)
#pragma unroll
        for (int fn = 0; fn < 4; ++fn) {
          acc1[fm][fn] = __builtin_amdgcn_mfma_f32_16x16x32_bf16(af1[fm], bfr[fn], acc1[fm][fn], 0, 0, 0);
          acc2[fm][fn] = __builtin_amdgcn_mfma_f32_16x16x32_bf16(af2[fm], bfr[fn], acc2[fm][fn], 0, 0, 0);
        }
    }
    __syncthreads();
  }

  // -------- epilogue: per-row online softmax partial over this 128-col tile ----
  // C layout (m89-verified): col = lane&15, row = quad*4 + reg within 16x16 frag.
#pragma unroll
  for (int fm = 0; fm < 4; ++fm) {
#pragma unroll
    for (int reg = 0; reg < 4; ++reg) {
      float v1[4], v2[4];
#pragma unroll
      for (int fn = 0; fn < 4; ++fn) { v1[fn] = acc1[fm][fn][reg]; v2[fn] = acc2[fm][fn][reg]; }
      float m1 = v1[0]; int b1 = 0;
      float m2 = v2[0]; int b2 = 0;
#pragma unroll
      for (int fn = 1; fn < 4; ++fn) {
        if (v1[fn] > m1) { m1 = v1[fn]; b1 = fn; }
        if (v2[fn] > m2) { m2 = v2[fn]; b2 = fn; }
      }
      float z1 = 0.f, tt = 0.f, z2 = 0.f;
#pragma unroll
      for (int fn = 0; fn < 4; ++fn) {
        float e1 = __expf(v1[fn] - m1);
        z1 += e1;
        tt += e1 * (v1[fn] - v2[fn]);
        z2 += __expf(v2[fn] - m2);
      }
      float i1 = (float)(n0 + wn * 64 + b1 * 16 + l15);
      float i2 = (float)(n0 + wn * 64 + b2 * 16 + l15);
#pragma unroll
      for (int mask = 1; mask <= 8; mask <<= 1) {
        float om1 = __shfl_xor(m1, mask, 64);
        float oz1 = __shfl_xor(z1, mask, 64);
        float ot = __shfl_xor(tt, mask, 64);
        float oi1 = __shfl_xor(i1, mask, 64);
        float om2 = __shfl_xor(m2, mask, 64);
        float oz2 = __shfl_xor(z2, mask, 64);
        float oi2 = __shfl_xor(i2, mask, 64);
        float nm1 = fmaxf(m1, om1);
        float ea = __expf(m1 - nm1), eb = __expf(om1 - nm1);
        z1 = z1 * ea + oz1 * eb;
        tt = tt * ea + ot * eb;
        if (om1 > m1) i1 = oi1;
        m1 = nm1;
        float nm2 = fmaxf(m2, om2);
        float ec = __expf(m2 - nm2), ed = __expf(om2 - nm2);
        z2 = z2 * ec + oz2 * ed;
        if (om2 > m2) i2 = oi2;
        m2 = nm2;
      }
      if (l15 == 0) {
        int row_local = wm * 64 + fm * 16 + quad * 4 + reg;
        float* r = &red[(row_local * 2 + wn) * 8];
        r[0] = m1; r[1] = z1; r[2] = tt; r[3] = i1; r[4] = m2; r[5] = z2; r[6] = i2;
      }
    }
  }
  __syncthreads();
  if (tid < 128) {
    const float* a = &red[(tid * 2 + 0) * 8];
    const float* b = &red[(tid * 2 + 1) * 8];
    float m1 = a[0], z1 = a[1], tt = a[2], i1 = a[3], m2 = a[4], z2 = a[5], i2 = a[6];
    {
      float om1 = b[0], oz1 = b[1], ot = b[2], oi1 = b[3], om2 = b[4], oz2 = b[5], oi2 = b[6];
      float nm1 = fmaxf(m1, om1);
      float ea = __expf(m1 - nm1), eb = __expf(om1 - nm1);
      z1 = z1 * ea + oz1 * eb;
      tt = tt * ea + ot * eb;
      if (om1 > m1) i1 = oi1;
      m1 = nm1;
      float nm2 = fmaxf(m2, om2);
      float ec = __expf(m2 - nm2), ed = __expf(om2 - nm2);
      z2 = z2 * ec + oz2 * ed;
      if (om2 > m2) i2 = oi2;
      m2 = nm2;
    }
    long idx = (long)blockIdx.y * N_TOK + (m0 + tid);
    pm1[idx] = m1; pz1[idx] = z1; pt[idx] = tt; pi1[idx] = i1;
    pm2[idx] = m2; pz2[idx] = z2; pi2[idx] = i2;
  }
}

// ---------------- per-token combine over vocab tiles ----------------
__global__ void token_combine(const float* __restrict__ pm1, const float* __restrict__ pz1,
                              const float* __restrict__ pt, const float* __restrict__ pi1,
                              const float* __restrict__ pm2, const float* __restrict__ pz2,
                              const float* __restrict__ pi2, const float* __restrict__ tl1,
                              const float* __restrict__ tl2, const int* __restrict__ tgt,
                              float* __restrict__ tout) {
  int t = blockIdx.x * blockDim.x + threadIdx.x;
  if (t >= N_TOK) return;
  float m1 = pm1[t], z1 = pz1[t], tt = pt[t], i1 = pi1[t];
  float m2 = pm2[t], z2 = pz2[t], i2 = pi2[t];
  for (int vt = 1; vt < NVT; ++vt) {
    long o = (long)vt * N_TOK + t;
    float om1 = pm1[o], oz1 = pz1[o], ot = pt[o], oi1 = pi1[o];
    float om2 = pm2[o], oz2 = pz2[o], oi2 = pi2[o];
    float nm1 = fmaxf(m1, om1);
    float ea = __expf(m1 - nm1), eb = __expf(om1 - nm1);
    z1 = z1 * ea + oz1 * eb;
    tt = tt * ea + ot * eb;
    if (om1 > m1) i1 = oi1;
    m1 = nm1;
    float nm2 = fmaxf(m2, om2);
    float ec = __expf(m2 - nm2), ed = __expf(om2 - nm2);
    z2 = z2 * ec + oz2 * ed;
    if (om2 > m2) i2 = oi2;
    m2 = nm2;
  }
  float lse1 = m1 + logf(z1);
  float lse2 = m2 + logf(z2);
  int g = tgt[t];
  float valid = (g != -100) ? 1.f : 0.f;
  float ce = (lse1 - tl1[t]) * valid;
  float mce = (lse2 - tl2[t]) * valid;
  float kl = (lse2 - lse1 + tt / z1) * valid;
  float ag = (i1 == i2) ? valid : 0.f;
  tout[t] = ce;
  tout[N_TOK + t] = mce;
  tout[2 * N_TOK + t] = kl;
  tout[3 * N_TOK + t] = ag;
  tout[4 * N_TOK + t] = valid;
}

// ---------------- final scalar reduction ----------------
__global__ void finalize(const float* __restrict__ tout, float* __restrict__ out) {
  __shared__ float sred[5][4];
  int tid = threadIdx.x;
  float s[5] = {0.f, 0.f, 0.f, 0.f, 0.f};
  for (int i = tid; i < N_TOK; i += 256)
#pragma unroll
    for (int k = 0; k < 5; ++k) s[k] += tout[k * N_TOK + i];
  for (int mask = 1; mask < 64; mask <<= 1)
#pragma unroll
    for (int k = 0; k < 5; ++k) s[k] += __shfl_xor(s[k], mask, 64);
  int wv = tid >> 6, lane = tid & 63;
  if (lane == 0)
#pragma unroll
    for (int k = 0; k < 5; ++k) sred[k][wv] = s[k];
  __syncthreads();
  if (tid == 0) {
    float ce = 0.f, mce = 0.f, kl = 0.f, ag = 0.f, nv = 0.f;
    for (int w = 0; w < 4; ++w) {
      ce += sred[0][w]; mce += sred[1][w]; kl += sred[2][w]; ag += sred[3][w]; nv += sred[4][w];
    }
    out[0] = (ce + 0.0f * mce + 1.0f * kl) / nv;  // MTP_CE_FACTOR=0, MTP_KL_FACTOR=1
    out[1] = ce / nv;
    out[2] = mce / nv;
    out[3] = kl / nv;
    out[4] = ag / nv;
  }
}

extern "C" void kernel_launch(void* const* d_in, const int* in_sizes, int n_in,
                              void* d_out, int out_size, void* d_ws, size_t ws_size,
                              hipStream_t stream) {
  const float* h1 = (const float*)d_in[0];   // outputs [4096,2048]
  const float* h2 = (const float*)d_in[1];   // mtp_outputs
  const float* W = (const float*)d_in[2];    // [32000,2048]
  const int* tgt = (const int*)d_in[3];      // [4096]
  float* out = (float*)d_out;
  char* ws = (char*)d_ws;

  const size_t OFF_W = 0;                                   // 131,072,000 B
  const size_t OFF_H1 = 131072000;                          // 16,777,216 B
  const size_t OFF_H2 = OFF_H1 + 16777216;
  const size_t OFF_P = OFF_H2 + 16777216;                   // 7 partial arrays
  const size_t PSZ = (size_t)NVT * N_TOK * 4;               // 4,096,000 B each
  const size_t OFF_TL1 = OFF_P + 7 * PSZ;
  const size_t OFF_TL2 = OFF_TL1 + (size_t)N_TOK * 4;
  const size_t OFF_TOUT = OFF_TL2 + (size_t)N_TOK * 4;

  __bf16* Wb = (__bf16*)(ws + OFF_W);
  __bf16* h1b = (__bf16*)(ws + OFF_H1);
  __bf16* h2b = (__bf16*)(ws + OFF_H2);
  float* pm1 = (float*)(ws + OFF_P + 0 * PSZ);
  float* pz1 = (float*)(ws + OFF_P + 1 * PSZ);
  float* pt = (float*)(ws + OFF_P + 2 * PSZ);
  float* pi1 = (float*)(ws + OFF_P + 3 * PSZ);
  float* pm2 = (float*)(ws + OFF_P + 4 * PSZ);
  float* pz2 = (float*)(ws + OFF_P + 5 * PSZ);
  float* pi2 = (float*)(ws + OFF_P + 6 * PSZ);
  float* tl1 = (float*)(ws + OFF_TL1);
  float* tl2 = (float*)(ws + OFF_TL2);
  float* tout = (float*)(ws + OFF_TOUT);

  // 1) bf16 conversions
  {
    long n8w = (long)V_DIM * D_DIM / 8;  // 8,192,000
    cvt_f32_bf16<<<(n8w + 255) / 256, 256, 0, stream>>>(W, Wb, n8w);
    long n8h = (long)N_TOK * D_DIM / 8;  // 1,048,576
    cvt_f32_bf16<<<(n8h + 255) / 256, 256, 0, stream>>>(h1, h1b, n8h);
    cvt_f32_bf16<<<(n8h + 255) / 256, 256, 0, stream>>>(h2, h2b, n8h);
  }
  // 2) target logits (fp32)
  tgt_dot<<<N_TOK / 4, 256, 0, stream>>>(h1, h2, W, tgt, tl1, tl2);
  // 3) fused dual-GEMM + tile partials
  {
    dim3 grid(NMT, NVT);
    fused_gemm<<<grid, 256, 0, stream>>>(h1b, h2b, Wb, pm1, pz1, pt, pi1, pm2, pz2, pi2);
  }
  // 4) per-token combine, 5) scalars
  token_combine<<<N_TOK / 256, 256, 0, stream>>>(pm1, pz1, pt, pi1, pm2, pz2, pi2, tl1, tl2, tgt, tout);
  finalize<<<1, 256, 0, stream>>>(tout, out);
}

// Round 2
// 1599.015 us; speedup vs baseline: 1.1196x; 1.1196x over previous
//
#include <hip/hip_runtime.h>
#include <hip/hip_bf16.h>

// LinearCEMTPLoss: logits = h @ W^T (and mtp), fused online-softmax CE/KL/argmax.
// B=2,S=2048 -> N=4096 tokens, D=2048, V=32000. Outputs: 5 fp32 scalars.
//
// R2: XOR-swizzled LDS layout (physical chunk16 = logical ^ (row&7)) to kill
// the 16-way ds_read_b128 bank conflicts seen in R1 (SQ_LDS_BANK_CONFLICT
// 2.96e8 -> expect ~0). Swizzle applied on the GLOBAL source address at
// staging time (global_load_lds dest must stay base+lane*16).

typedef __bf16 bf16x8 __attribute__((ext_vector_type(8)));
typedef float f32x4 __attribute__((ext_vector_type(4)));

#define D_DIM 2048
#define N_TOK 4096
#define V_DIM 32000
#define NVT 250   /* 32000/128 vocab tiles */
#define NMT 32    /* 4096/128 token tiles */

__device__ __forceinline__ void async_ld16(const void* g, void* l) {
  __builtin_amdgcn_global_load_lds(
      (const __attribute__((address_space(1))) unsigned int*)g,
      (__attribute__((address_space(3))) unsigned int*)l, 16, 0, 0);
}

// ---------------- fp32 -> bf16 convert (8 elems/thread) ----------------
__global__ void cvt_f32_bf16(const float* __restrict__ s, __bf16* __restrict__ d, long n8) {
  long i = (long)blockIdx.x * blockDim.x + threadIdx.x;
  if (i >= n8) return;
  const float4* s4 = (const float4*)s;
  float4 a = s4[2 * i], b = s4[2 * i + 1];
  bf16x8 o;
  o[0] = (__bf16)a.x; o[1] = (__bf16)a.y; o[2] = (__bf16)a.z; o[3] = (__bf16)a.w;
  o[4] = (__bf16)b.x; o[5] = (__bf16)b.y; o[6] = (__bf16)b.z; o[7] = (__bf16)b.w;
  *(bf16x8*)(d + i * 8) = o;
}

// ---------------- target-logit dot (fp32, 1 wave/token) ----------------
__global__ void tgt_dot(const float* __restrict__ h, const float* __restrict__ mtp,
                        const float* __restrict__ W, const int* __restrict__ tgt,
                        float* __restrict__ tl1, float* __restrict__ tl2) {
  int token = blockIdx.x * 4 + (threadIdx.x >> 6);
  int lane = threadIdx.x & 63;
  int g = tgt[token];
  int sg = g < 0 ? 0 : g;
  const float4* hr = (const float4*)(h + (long)token * D_DIM);
  const float4* mr = (const float4*)(mtp + (long)token * D_DIM);
  const float4* wr = (const float4*)(W + (long)sg * D_DIM);
  float s1 = 0.f, s2 = 0.f;
#pragma unroll
  for (int c = 0; c < 8; ++c) {
    int j = lane + c * 64;
    float4 w = wr[j], a = hr[j], b = mr[j];
    s1 += a.x * w.x + a.y * w.y + a.z * w.z + a.w * w.w;
    s2 += b.x * w.x + b.y * w.y + b.z * w.z + b.w * w.w;
  }
  for (int mask = 1; mask < 64; mask <<= 1) {
    s1 += __shfl_xor(s1, mask, 64);
    s2 += __shfl_xor(s2, mask, 64);
  }
  if (lane == 0) { tl1[token] = s1; tl2[token] = s2; }
}

// ---------------- fused dual GEMM + online softmax partials ----------------
// grid: (NMT token tiles, NVT vocab tiles); block 256 = 4 waves (2x2), wave=64x64.
__global__ __launch_bounds__(256, 2) void fused_gemm(
    const __bf16* __restrict__ A1, const __bf16* __restrict__ A2,
    const __bf16* __restrict__ Bw,
    float* __restrict__ pm1, float* __restrict__ pz1, float* __restrict__ pt,
    float* __restrict__ pi1, float* __restrict__ pm2, float* __restrict__ pz2,
    float* __restrict__ pi2) {
  __shared__ __align__(16) __bf16 sA1[128 * 64];
  __shared__ __align__(16) __bf16 sA2[128 * 64];
  __shared__ __align__(16) __bf16 sB[128 * 64];
  __shared__ float red[128 * 2 * 8];

  const int tid = threadIdx.x;
  const int wave = tid >> 6;
  const int lane = tid & 63;
  const int wm = wave & 1, wn = wave >> 1;
  const int quad = lane >> 4, l15 = lane & 15;

  const int m0 = blockIdx.x * 128;  // token tile base
  const int n0 = blockIdx.y * 128;  // vocab tile base

  // staging: wave w loads rows [w*32, w*32+32) of each tile; 8 rows/instr.
  // Lane writes LDS physical (row = lane>>3, chunk16 = lane&7); with the
  // XOR swizzle (phys = logical ^ (row&7)), it must FETCH logical chunk
  // (lane&7) ^ (lane>>3) from global.
  const int srow = wave * 32 + (lane >> 3);
  const int schunk = (lane & 7) ^ ((lane >> 3) & 7);
  const __bf16* gA1 = A1 + (long)(m0 + srow) * D_DIM + schunk * 8;
  const __bf16* gA2 = A2 + (long)(m0 + srow) * D_DIM + schunk * 8;
  const __bf16* gB = Bw + (long)(n0 + srow) * D_DIM + schunk * 8;

  f32x4 acc1[4][4], acc2[4][4];
#pragma unroll
  for (int a = 0; a < 4; ++a)
#pragma unroll
    for (int b = 0; b < 4; ++b) {
      acc1[a][b] = (f32x4){0.f, 0.f, 0.f, 0.f};
      acc2[a][b] = (f32x4){0.f, 0.f, 0.f, 0.f};
    }

  const int sw = l15 & 7;  // read-side swizzle key (row&7 == l15&7 for all frags)

  for (int ks = 0; ks < D_DIM / 64; ++ks) {
    const int koff = ks * 64;
#pragma unroll
    for (int i = 0; i < 4; ++i) {
      async_ld16(gA1 + (long)i * 8 * D_DIM + koff, &sA1[(wave * 32 + i * 8) * 64]);
      async_ld16(gA2 + (long)i * 8 * D_DIM + koff, &sA2[(wave * 32 + i * 8) * 64]);
      async_ld16(gB + (long)i * 8 * D_DIM + koff, &sB[(wave * 32 + i * 8) * 64]);
    }
    __syncthreads();
#pragma unroll
    for (int kk = 0; kk < 2; ++kk) {
      bf16x8 af1[4], af2[4], bfr[4];
#pragma unroll
      for (int f = 0; f < 4; ++f) {
        const int pc = ((kk * 4 + quad) ^ sw) * 8;  // swizzled chunk offset (elems)
        af1[f] = *(const bf16x8*)&sA1[(wm * 64 + f * 16 + l15) * 64 + pc];
        af2[f] = *(const bf16x8*)&sA2[(wm * 64 + f * 16 + l15) * 64 + pc];
        bfr[f] = *(const bf16x8*)&sB[(wn * 64 + f * 16 + l15) * 64 + pc];
      }
#pragma unroll
      for (int fm = 0; fm < 4; ++fm)
#pragma unroll
        for (int fn = 0; fn < 4; ++fn) {
          acc1[fm][fn] = __builtin_amdgcn_mfma_f32_16x16x32_bf16(af1[fm], bfr[fn], acc1[fm][fn], 0, 0, 0);
          acc2[fm][fn] = __builtin_amdgcn_mfma_f32_16x16x32_bf16(af2[fm], bfr[fn], acc2[fm][fn], 0, 0, 0);
        }
    }
    __syncthreads();
  }

  // -------- epilogue: per-row online softmax partial over this 128-col tile ----
  // C layout (m89-verified): col = lane&15, row = quad*4 + reg within 16x16 frag.
#pragma unroll
  for (int fm = 0; fm < 4; ++fm) {
#pragma unroll
    for (int reg = 0; reg < 4; ++reg) {
      float v1[4], v2[4];
#pragma unroll
      for (int fn = 0; fn < 4; ++fn) { v1[fn] = acc1[fm][fn][reg]; v2[fn] = acc2[fm][fn][reg]; }
      float m1 = v1[0]; int b1 = 0;
      float m2 = v2[0]; int b2 = 0;
#pragma unroll
      for (int fn = 1; fn < 4; ++fn) {
        if (v1[fn] > m1) { m1 = v1[fn]; b1 = fn; }
        if (v2[fn] > m2) { m2 = v2[fn]; b2 = fn; }
      }
      float z1 = 0.f, tt = 0.f, z2 = 0.f;
#pragma unroll
      for (int fn = 0; fn < 4; ++fn) {
        float e1 = __expf(v1[fn] - m1);
        z1 += e1;
        tt += e1 * (v1[fn] - v2[fn]);
        z2 += __expf(v2[fn] - m2);
      }
      float i1 = (float)(n0 + wn * 64 + b1 * 16 + l15);
      float i2 = (float)(n0 + wn * 64 + b2 * 16 + l15);
#pragma unroll
      for (int mask = 1; mask <= 8; mask <<= 1) {
        float om1 = __shfl_xor(m1, mask, 64);
        float oz1 = __shfl_xor(z1, mask, 64);
        float ot = __shfl_xor(tt, mask, 64);
        float oi1 = __shfl_xor(i1, mask, 64);
        float om2 = __shfl_xor(m2, mask, 64);
        float oz2 = __shfl_xor(z2, mask, 64);
        float oi2 = __shfl_xor(i2, mask, 64);
        float nm1 = fmaxf(m1, om1);
        float ea = __expf(m1 - nm1), eb = __expf(om1 - nm1);
        z1 = z1 * ea + oz1 * eb;
        tt = tt * ea + ot * eb;
        if (om1 > m1) i1 = oi1;
        m1 = nm1;
        float nm2 = fmaxf(m2, om2);
        float ec = __expf(m2 - nm2), ed = __expf(om2 - nm2);
        z2 = z2 * ec + oz2 * ed;
        if (om2 > m2) i2 = oi2;
        m2 = nm2;
      }
      if (l15 == 0) {
        int row_local = wm * 64 + fm * 16 + quad * 4 + reg;
        float* r = &red[(row_local * 2 + wn) * 8];
        r[0] = m1; r[1] = z1; r[2] = tt; r[3] = i1; r[4] = m2; r[5] = z2; r[6] = i2;
      }
    }
  }
  __syncthreads();
  if (tid < 128) {
    const float* a = &red[(tid * 2 + 0) * 8];
    const float* b = &red[(tid * 2 + 1) * 8];
    float m1 = a[0], z1 = a[1], tt = a[2], i1 = a[3], m2 = a[4], z2 = a[5], i2 = a[6];
    {
      float om1 = b[0], oz1 = b[1], ot = b[2], oi1 = b[3], om2 = b[4], oz2 = b[5], oi2 = b[6];
      float nm1 = fmaxf(m1, om1);
      float ea = __expf(m1 - nm1), eb = __expf(om1 - nm1);
      z1 = z1 * ea + oz1 * eb;
      tt = tt * ea + ot * eb;
      if (om1 > m1) i1 = oi1;
      m1 = nm1;
      float nm2 = fmaxf(m2, om2);
      float ec = __expf(m2 - nm2), ed = __expf(om2 - nm2);
      z2 = z2 * ec + oz2 * ed;
      if (om2 > m2) i2 = oi2;
      m2 = nm2;
    }
    long idx = (long)blockIdx.y * N_TOK + (m0 + tid);
    pm1[idx] = m1; pz1[idx] = z1; pt[idx] = tt; pi1[idx] = i1;
    pm2[idx] = m2; pz2[idx] = z2; pi2[idx] = i2;
  }
}

// ---------------- per-token combine over vocab tiles ----------------
__global__ void token_combine(const float* __restrict__ pm1, const float* __restrict__ pz1,
                              const float* __restrict__ pt, const float* __restrict__ pi1,
                              const float* __restrict__ pm2, const float* __restrict__ pz2,
                              const float* __restrict__ pi2, const float* __restrict__ tl1,
                              const float* __restrict__ tl2, const int* __restrict__ tgt,
                              float* __restrict__ tout) {
  int t = blockIdx.x * blockDim.x + threadIdx.x;
  if (t >= N_TOK) return;
  float m1 = pm1[t], z1 = pz1[t], tt = pt[t], i1 = pi1[t];
  float m2 = pm2[t], z2 = pz2[t], i2 = pi2[t];
  for (int vt = 1; vt < NVT; ++vt) {
    long o = (long)vt * N_TOK + t;
    float om1 = pm1[o], oz1 = pz1[o], ot = pt[o], oi1 = pi1[o];
    float om2 = pm2[o], oz2 = pz2[o], oi2 = pi2[o];
    float nm1 = fmaxf(m1, om1);
    float ea = __expf(m1 - nm1), eb = __expf(om1 - nm1);
    z1 = z1 * ea + oz1 * eb;
    tt = tt * ea + ot * eb;
    if (om1 > m1) i1 = oi1;
    m1 = nm1;
    float nm2 = fmaxf(m2, om2);
    float ec = __expf(m2 - nm2), ed = __expf(om2 - nm2);
    z2 = z2 * ec + oz2 * ed;
    if (om2 > m2) i2 = oi2;
    m2 = nm2;
  }
  float lse1 = m1 + logf(z1);
  float lse2 = m2 + logf(z2);
  int g = tgt[t];
  float valid = (g != -100) ? 1.f : 0.f;
  float ce = (lse1 - tl1[t]) * valid;
  float mce = (lse2 - tl2[t]) * valid;
  float kl = (lse2 - lse1 + tt / z1) * valid;
  float ag = (i1 == i2) ? valid : 0.f;
  tout[t] = ce;
  tout[N_TOK + t] = mce;
  tout[2 * N_TOK + t] = kl;
  tout[3 * N_TOK + t] = ag;
  tout[4 * N_TOK + t] = valid;
}

// ---------------- final scalar reduction ----------------
__global__ void finalize(const float* __restrict__ tout, float* __restrict__ out) {
  __shared__ float sred[5][4];
  int tid = threadIdx.x;
  float s[5] = {0.f, 0.f, 0.f, 0.f, 0.f};
  for (int i = tid; i < N_TOK; i += 256)
#pragma unroll
    for (int k = 0; k < 5; ++k) s[k] += tout[k * N_TOK + i];
  for (int mask = 1; mask < 64; mask <<= 1)
#pragma unroll
    for (int k = 0; k < 5; ++k) s[k] += __shfl_xor(s[k], mask, 64);
  int wv = tid >> 6, lane = tid & 63;
  if (lane == 0)
#pragma unroll
    for (int k = 0; k < 5; ++k) sred[k][wv] = s[k];
  __syncthreads();
  if (tid == 0) {
    float ce = 0.f, mce = 0.f, kl = 0.f, ag = 0.f, nv = 0.f;
    for (int w = 0; w < 4; ++w) {
      ce += sred[0][w]; mce += sred[1][w]; kl += sred[2][w]; ag += sred[3][w]; nv += sred[4][w];
    }
    out[0] = (ce + 0.0f * mce + 1.0f * kl) / nv;  // MTP_CE_FACTOR=0, MTP_KL_FACTOR=1
    out[1] = ce / nv;
    out[2] = mce / nv;
    out[3] = kl / nv;
    out[4] = ag / nv;
  }
}

extern "C" void kernel_launch(void* const* d_in, const int* in_sizes, int n_in,
                              void* d_out, int out_size, void* d_ws, size_t ws_size,
                              hipStream_t stream) {
  const float* h1 = (const float*)d_in[0];   // outputs [4096,2048]
  const float* h2 = (const float*)d_in[1];   // mtp_outputs
  const float* W = (const float*)d_in[2];    // [32000,2048]
  const int* tgt = (const int*)d_in[3];      // [4096]
  float* out = (float*)d_out;
  char* ws = (char*)d_ws;

  const size_t OFF_W = 0;                                   // 131,072,000 B
  const size_t OFF_H1 = 131072000;                          // 16,777,216 B
  const size_t OFF_H2 = OFF_H1 + 16777216;
  const size_t OFF_P = OFF_H2 + 16777216;                   // 7 partial arrays
  const size_t PSZ = (size_t)NVT * N_TOK * 4;               // 4,096,000 B each
  const size_t OFF_TL1 = OFF_P + 7 * PSZ;
  const size_t OFF_TL2 = OFF_TL1 + (size_t)N_TOK * 4;
  const size_t OFF_TOUT = OFF_TL2 + (size_t)N_TOK * 4;

  __bf16* Wb = (__bf16*)(ws + OFF_W);
  __bf16* h1b = (__bf16*)(ws + OFF_H1);
  __bf16* h2b = (__bf16*)(ws + OFF_H2);
  float* pm1 = (float*)(ws + OFF_P + 0 * PSZ);
  float* pz1 = (float*)(ws + OFF_P + 1 * PSZ);
  float* pt = (float*)(ws + OFF_P + 2 * PSZ);
  float* pi1 = (float*)(ws + OFF_P + 3 * PSZ);
  float* pm2 = (float*)(ws + OFF_P + 4 * PSZ);
  float* pz2 = (float*)(ws + OFF_P + 5 * PSZ);
  float* pi2 = (float*)(ws + OFF_P + 6 * PSZ);
  float* tl1 = (float*)(ws + OFF_TL1);
  float* tl2 = (float*)(ws + OFF_TL2);
  float* tout = (float*)(ws + OFF_TOUT);

  // 1) bf16 conversions
  {
    long n8w = (long)V_DIM * D_DIM / 8;  // 8,192,000
    cvt_f32_bf16<<<(n8w + 255) / 256, 256, 0, stream>>>(W, Wb, n8w);
    long n8h = (long)N_TOK * D_DIM / 8;  // 1,048,576
    cvt_f32_bf16<<<(n8h + 255) / 256, 256, 0, stream>>>(h1, h1b, n8h);
    cvt_f32_bf16<<<(n8h + 255) / 256, 256, 0, stream>>>(h2, h2b, n8h);
  }
  // 2) target logits (fp32)
  tgt_dot<<<N_TOK / 4, 256, 0, stream>>>(h1, h2, W, tgt, tl1, tl2);
  // 3) fused dual-GEMM + tile partials
  {
    dim3 grid(NMT, NVT);
    fused_gemm<<<grid, 256, 0, stream>>>(h1b, h2b, Wb, pm1, pz1, pt, pi1, pm2, pz2, pi2);
  }
  // 4) per-token combine, 5) scalars
  token_combine<<<N_TOK / 256, 256, 0, stream>>>(pm1, pz1, pt, pi1, pm2, pz2, pi2, tl1, tl2, tgt, tout);
  finalize<<<1, 256, 0, stream>>>(tout, out);
}

// Round 3
// 1190.998 us; speedup vs baseline: 1.5032x; 1.3426x over previous
//
#include <hip/hip_runtime.h>
#include <hip/hip_bf16.h>

// LinearCEMTPLoss: logits = h @ W^T (and mtp), fused online-softmax CE/KL/argmax.
// B=2,S=2048 -> N=4096 tokens, D=2048, V=32000. Outputs: 5 fp32 scalars.
//
// R3: MX-fp8 path. Quantize h (scale 1) and W (scale 64, pow2) to fp8 e4m3;
// K-loop uses mfma_scale_f32_16x16x128_f8f6f4 with unit e8m0 scales
// (0x7F7F7F7F) -> plain fp8 GEMM at the MX K=128 rate (m148: 1628 TF vs
// bf16's 890 TF plateau). LDS bytes/K halve; XOR swizzle retained.
// Epilogue multiplies acc by 1/64 before softmax; target logits stay fp32.

typedef float f32x4 __attribute__((ext_vector_type(4)));
typedef int v8i __attribute__((ext_vector_type(8)));

#define D_DIM 2048
#define N_TOK 4096
#define V_DIM 32000
#define NVT 250   /* 32000/128 vocab tiles */
#define NMT 32    /* 4096/128 token tiles */

#define W_SCALE 64.0f
#define INV_W_SCALE 0.015625f
#define UNIT_SCALES 0x7F7F7F7F  /* four e8m0 = 1.0 */

__device__ __forceinline__ void async_ld16(const void* g, void* l) {
  __builtin_amdgcn_global_load_lds(
      (const __attribute__((address_space(1))) unsigned int*)g,
      (__attribute__((address_space(3))) unsigned int*)l, 16, 0, 0);
}

// ---------------- fp32 -> fp8 e4m3 convert (16 elems/thread), scaled ------
__global__ void cvt_f32_fp8(const float* __restrict__ s, unsigned char* __restrict__ d,
                            float scale, long n16) {
  long i = (long)blockIdx.x * blockDim.x + threadIdx.x;
  if (i >= n16) return;
  const float4* s4 = (const float4*)s + 4 * i;
  float4 a = s4[0], b = s4[1], c = s4[2], e = s4[3];
  int w0 = __builtin_amdgcn_cvt_pk_fp8_f32(a.x * scale, a.y * scale, 0, 0);
  w0 = __builtin_amdgcn_cvt_pk_fp8_f32(a.z * scale, a.w * scale, w0, 1);
  int w1 = __builtin_amdgcn_cvt_pk_fp8_f32(b.x * scale, b.y * scale, 0, 0);
  w1 = __builtin_amdgcn_cvt_pk_fp8_f32(b.z * scale, b.w * scale, w1, 1);
  int w2 = __builtin_amdgcn_cvt_pk_fp8_f32(c.x * scale, c.y * scale, 0, 0);
  w2 = __builtin_amdgcn_cvt_pk_fp8_f32(c.z * scale, c.w * scale, w2, 1);
  int w3 = __builtin_amdgcn_cvt_pk_fp8_f32(e.x * scale, e.y * scale, 0, 0);
  w3 = __builtin_amdgcn_cvt_pk_fp8_f32(e.z * scale, e.w * scale, w3, 1);
  int4 o; o.x = w0; o.y = w1; o.z = w2; o.w = w3;
  *(int4*)(d + 16 * i) = o;
}

// ---------------- target-logit dot (fp32, 1 wave/token) ----------------
__global__ void tgt_dot(const float* __restrict__ h, const float* __restrict__ mtp,
                        const float* __restrict__ W, const int* __restrict__ tgt,
                        float* __restrict__ tl1, float* __restrict__ tl2) {
  int token = blockIdx.x * 4 + (threadIdx.x >> 6);
  int lane = threadIdx.x & 63;
  int g = tgt[token];
  int sg = g < 0 ? 0 : g;
  const float4* hr = (const float4*)(h + (long)token * D_DIM);
  const float4* mr = (const float4*)(mtp + (long)token * D_DIM);
  const float4* wr = (const float4*)(W + (long)sg * D_DIM);
  float s1 = 0.f, s2 = 0.f;
#pragma unroll
  for (int c = 0; c < 8; ++c) {
    int j = lane + c * 64;
    float4 w = wr[j], a = hr[j], b = mr[j];
    s1 += a.x * w.x + a.y * w.y + a.z * w.z + a.w * w.w;
    s2 += b.x * w.x + b.y * w.y + b.z * w.z + b.w * w.w;
  }
  for (int mask = 1; mask < 64; mask <<= 1) {
    s1 += __shfl_xor(s1, mask, 64);
    s2 += __shfl_xor(s2, mask, 64);
  }
  if (lane == 0) { tl1[token] = s1; tl2[token] = s2; }
}

// ---------------- fused dual GEMM (fp8, K=128 MFMA) + softmax partials ------
// grid: (NMT token tiles, NVT vocab tiles); block 256 = 4 waves (2x2), wave=64x64.
__global__ __launch_bounds__(256, 2) void fused_gemm(
    const unsigned char* __restrict__ A1, const unsigned char* __restrict__ A2,
    const unsigned char* __restrict__ Bw,
    float* __restrict__ pm1, float* __restrict__ pz1, float* __restrict__ pt,
    float* __restrict__ pi1, float* __restrict__ pm2, float* __restrict__ pz2,
    float* __restrict__ pi2) {
  __shared__ __align__(16) unsigned char sA1[128 * 128];
  __shared__ __align__(16) unsigned char sA2[128 * 128];
  __shared__ __align__(16) unsigned char sB[128 * 128];
  __shared__ float red[128 * 2 * 8];

  const int tid = threadIdx.x;
  const int wave = tid >> 6;
  const int lane = tid & 63;
  const int wm = wave & 1, wn = wave >> 1;
  const int quad = lane >> 4, l15 = lane & 15;

  const int m0 = blockIdx.x * 128;  // token tile base
  const int n0 = blockIdx.y * 128;  // vocab tile base

  // staging: wave w loads rows [w*32, w*32+32); row = 128 B = 8 chunks of 16 B.
  // LDS physical chunk = lane&7; XOR swizzle (phys = logical ^ (row&7)) done
  // by fetching logical chunk (lane&7)^((lane>>3)&7) from global.
  const int srow = wave * 32 + (lane >> 3);
  const int schunk = (lane & 7) ^ ((lane >> 3) & 7);
  const unsigned char* gA1 = A1 + (long)(m0 + srow) * D_DIM + schunk * 16;
  const unsigned char* gA2 = A2 + (long)(m0 + srow) * D_DIM + schunk * 16;
  const unsigned char* gB = Bw + (long)(n0 + srow) * D_DIM + schunk * 16;

  f32x4 acc1[4][4], acc2[4][4];
#pragma unroll
  for (int a = 0; a < 4; ++a)
#pragma unroll
    for (int b = 0; b < 4; ++b) {
      acc1[a][b] = (f32x4){0.f, 0.f, 0.f, 0.f};
      acc2[a][b] = (f32x4){0.f, 0.f, 0.f, 0.f};
    }

  const int sw = l15 & 7;  // read-side swizzle key (row&7 == l15&7 for all frags)

  for (int ks = 0; ks < D_DIM / 128; ++ks) {
    const int koff = ks * 128;
#pragma unroll
    for (int i = 0; i < 4; ++i) {
      async_ld16(gA1 + (long)i * 8 * D_DIM + koff, &sA1[(wave * 32 + i * 8) * 128]);
      async_ld16(gA2 + (long)i * 8 * D_DIM + koff, &sA2[(wave * 32 + i * 8) * 128]);
      async_ld16(gB + (long)i * 8 * D_DIM + koff, &sB[(wave * 32 + i * 8) * 128]);
    }
    __syncthreads();
    // B fragments for this wave's 64 cols: lane holds k = quad*32 + [0..32).
    v8i bfr[4];
#pragma unroll
    for (int f = 0; f < 4; ++f) {
      const int rb = (wn * 64 + f * 16 + l15) * 128;
      int4 lo = *(const int4*)&sB[rb + ((quad * 2 + 0) ^ sw) * 16];
      int4 hi = *(const int4*)&sB[rb + ((quad * 2 + 1) ^ sw) * 16];
      bfr[f] = (v8i){lo.x, lo.y, lo.z, lo.w, hi.x, hi.y, hi.z, hi.w};
    }
#pragma unroll
    for (int fm = 0; fm < 4; ++fm) {
      const int ra = (wm * 64 + fm * 16 + l15) * 128;
      int4 lo1 = *(const int4*)&sA1[ra + ((quad * 2 + 0) ^ sw) * 16];
      int4 hi1 = *(const int4*)&sA1[ra + ((quad * 2 + 1) ^ sw) * 16];
      int4 lo2 = *(const int4*)&sA2[ra + ((quad * 2 + 0) ^ sw) * 16];
      int4 hi2 = *(const int4*)&sA2[ra + ((quad * 2 + 1) ^ sw) * 16];
      v8i af1 = (v8i){lo1.x, lo1.y, lo1.z, lo1.w, hi1.x, hi1.y, hi1.z, hi1.w};
      v8i af2 = (v8i){lo2.x, lo2.y, lo2.z, lo2.w, hi2.x, hi2.y, hi2.z, hi2.w};
#pragma unroll
      for (int fn = 0; fn < 4; ++fn) {
        acc1[fm][fn] = __builtin_amdgcn_mfma_scale_f32_16x16x128_f8f6f4(
            af1, bfr[fn], acc1[fm][fn], 0, 0, 0, UNIT_SCALES, 0, UNIT_SCALES);
        acc2[fm][fn] = __builtin_amdgcn_mfma_scale_f32_16x16x128_f8f6f4(
            af2, bfr[fn], acc2[fm][fn], 0, 0, 0, UNIT_SCALES, 0, UNIT_SCALES);
      }
    }
    __syncthreads();
  }

  // -------- epilogue: per-row online softmax partial over this 128-col tile ----
  // C layout (m89/m127-verified, shape-determined): col = lane&15, row = quad*4+reg.
#pragma unroll
  for (int fm = 0; fm < 4; ++fm) {
#pragma unroll
    for (int reg = 0; reg < 4; ++reg) {
      float v1[4], v2[4];
#pragma unroll
      for (int fn = 0; fn < 4; ++fn) {
        v1[fn] = acc1[fm][fn][reg] * INV_W_SCALE;
        v2[fn] = acc2[fm][fn][reg] * INV_W_SCALE;
      }
      float m1 = v1[0]; int b1 = 0;
      float m2 = v2[0]; int b2 = 0;
#pragma unroll
      for (int fn = 1; fn < 4; ++fn) {
        if (v1[fn] > m1) { m1 = v1[fn]; b1 = fn; }
        if (v2[fn] > m2) { m2 = v2[fn]; b2 = fn; }
      }
      float z1 = 0.f, tt = 0.f, z2 = 0.f;
#pragma unroll
      for (int fn = 0; fn < 4; ++fn) {
        float e1 = __expf(v1[fn] - m1);
        z1 += e1;
        tt += e1 * (v1[fn] - v2[fn]);
        z2 += __expf(v2[fn] - m2);
      }
      float i1 = (float)(n0 + wn * 64 + b1 * 16 + l15);
      float i2 = (float)(n0 + wn * 64 + b2 * 16 + l15);
#pragma unroll
      for (int mask = 1; mask <= 8; mask <<= 1) {
        float om1 = __shfl_xor(m1, mask, 64);
        float oz1 = __shfl_xor(z1, mask, 64);
        float ot = __shfl_xor(tt, mask, 64);
        float oi1 = __shfl_xor(i1, mask, 64);
        float om2 = __shfl_xor(m2, mask, 64);
        float oz2 = __shfl_xor(z2, mask, 64);
        float oi2 = __shfl_xor(i2, mask, 64);
        float nm1 = fmaxf(m1, om1);
        float ea = __expf(m1 - nm1), eb = __expf(om1 - nm1);
        z1 = z1 * ea + oz1 * eb;
        tt = tt * ea + ot * eb;
        if (om1 > m1) i1 = oi1;
        m1 = nm1;
        float nm2 = fmaxf(m2, om2);
        float ec = __expf(m2 - nm2), ed = __expf(om2 - nm2);
        z2 = z2 * ec + oz2 * ed;
        if (om2 > m2) i2 = oi2;
        m2 = nm2;
      }
      if (l15 == 0) {
        int row_local = wm * 64 + fm * 16 + quad * 4 + reg;
        float* r = &red[(row_local * 2 + wn) * 8];
        r[0] = m1; r[1] = z1; r[2] = tt; r[3] = i1; r[4] = m2; r[5] = z2; r[6] = i2;
      }
    }
  }
  __syncthreads();
  if (tid < 128) {
    const float* a = &red[(tid * 2 + 0) * 8];
    const float* b = &red[(tid * 2 + 1) * 8];
    float m1 = a[0], z1 = a[1], tt = a[2], i1 = a[3], m2 = a[4], z2 = a[5], i2 = a[6];
    {
      float om1 = b[0], oz1 = b[1], ot = b[2], oi1 = b[3], om2 = b[4], oz2 = b[5], oi2 = b[6];
      float nm1 = fmaxf(m1, om1);
      float ea = __expf(m1 - nm1), eb = __expf(om1 - nm1);
      z1 = z1 * ea + oz1 * eb;
      tt = tt * ea + ot * eb;
      if (om1 > m1) i1 = oi1;
      m1 = nm1;
      float nm2 = fmaxf(m2, om2);
      float ec = __expf(m2 - nm2), ed = __expf(om2 - nm2);
      z2 = z2 * ec + oz2 * ed;
      if (om2 > m2) i2 = oi2;
      m2 = nm2;
    }
    long idx = (long)blockIdx.y * N_TOK + (m0 + tid);
    pm1[idx] = m1; pz1[idx] = z1; pt[idx] = tt; pi1[idx] = i1;
    pm2[idx] = m2; pz2[idx] = z2; pi2[idx] = i2;
  }
}

// ---------------- per-token combine over vocab tiles ----------------
__global__ void token_combine(const float* __restrict__ pm1, const float* __restrict__ pz1,
                              const float* __restrict__ pt, const float* __restrict__ pi1,
                              const float* __restrict__ pm2, const float* __restrict__ pz2,
                              const float* __restrict__ pi2, const float* __restrict__ tl1,
                              const float* __restrict__ tl2, const int* __restrict__ tgt,
                              float* __restrict__ tout) {
  int t = blockIdx.x * blockDim.x + threadIdx.x;
  if (t >= N_TOK) return;
  float m1 = pm1[t], z1 = pz1[t], tt = pt[t], i1 = pi1[t];
  float m2 = pm2[t], z2 = pz2[t], i2 = pi2[t];
  for (int vt = 1; vt < NVT; ++vt) {
    long o = (long)vt * N_TOK + t;
    float om1 = pm1[o], oz1 = pz1[o], ot = pt[o], oi1 = pi1[o];
    float om2 = pm2[o], oz2 = pz2[o], oi2 = pi2[o];
    float nm1 = fmaxf(m1, om1);
    float ea = __expf(m1 - nm1), eb = __expf(om1 - nm1);
    z1 = z1 * ea + oz1 * eb;
    tt = tt * ea + ot * eb;
    if (om1 > m1) i1 = oi1;
    m1 = nm1;
    float nm2 = fmaxf(m2, om2);
    float ec = __expf(m2 - nm2), ed = __expf(om2 - nm2);
    z2 = z2 * ec + oz2 * ed;
    if (om2 > m2) i2 = oi2;
    m2 = nm2;
  }
  float lse1 = m1 + logf(z1);
  float lse2 = m2 + logf(z2);
  int g = tgt[t];
  float valid = (g != -100) ? 1.f : 0.f;
  float ce = (lse1 - tl1[t]) * valid;
  float mce = (lse2 - tl2[t]) * valid;
  float kl = (lse2 - lse1 + tt / z1) * valid;
  float ag = (i1 == i2) ? valid : 0.f;
  tout[t] = ce;
  tout[N_TOK + t] = mce;
  tout[2 * N_TOK + t] = kl;
  tout[3 * N_TOK + t] = ag;
  tout[4 * N_TOK + t] = valid;
}

// ---------------- final scalar reduction ----------------
__global__ void finalize(const float* __restrict__ tout, float* __restrict__ out) {
  __shared__ float sred[5][4];
  int tid = threadIdx.x;
  float s[5] = {0.f, 0.f, 0.f, 0.f, 0.f};
  for (int i = tid; i < N_TOK; i += 256)
#pragma unroll
    for (int k = 0; k < 5; ++k) s[k] += tout[k * N_TOK + i];
  for (int mask = 1; mask < 64; mask <<= 1)
#pragma unroll
    for (int k = 0; k < 5; ++k) s[k] += __shfl_xor(s[k], mask, 64);
  int wv = tid >> 6, lane = tid & 63;
  if (lane == 0)
#pragma unroll
    for (int k = 0; k < 5; ++k) sred[k][wv] = s[k];
  __syncthreads();
  if (tid == 0) {
    float ce = 0.f, mce = 0.f, kl = 0.f, ag = 0.f, nv = 0.f;
    for (int w = 0; w < 4; ++w) {
      ce += sred[0][w]; mce += sred[1][w]; kl += sred[2][w]; ag += sred[3][w]; nv += sred[4][w];
    }
    out[0] = (ce + 0.0f * mce + 1.0f * kl) / nv;  // MTP_CE_FACTOR=0, MTP_KL_FACTOR=1
    out[1] = ce / nv;
    out[2] = mce / nv;
    out[3] = kl / nv;
    out[4] = ag / nv;
  }
}

extern "C" void kernel_launch(void* const* d_in, const int* in_sizes, int n_in,
                              void* d_out, int out_size, void* d_ws, size_t ws_size,
                              hipStream_t stream) {
  const float* h1 = (const float*)d_in[0];   // outputs [4096,2048]
  const float* h2 = (const float*)d_in[1];   // mtp_outputs
  const float* W = (const float*)d_in[2];    // [32000,2048]
  const int* tgt = (const int*)d_in[3];      // [4096]
  float* out = (float*)d_out;
  char* ws = (char*)d_ws;

  const size_t OFF_W = 0;                                   // 65,536,000 B (fp8)
  const size_t OFF_H1 = 65536000;                           // 8,388,608 B each
  const size_t OFF_H2 = OFF_H1 + 8388608;
  const size_t OFF_P = OFF_H2 + 8388608;                    // 7 partial arrays
  const size_t PSZ = (size_t)NVT * N_TOK * 4;               // 4,096,000 B each
  const size_t OFF_TL1 = OFF_P + 7 * PSZ;
  const size_t OFF_TL2 = OFF_TL1 + (size_t)N_TOK * 4;
  const size_t OFF_TOUT = OFF_TL2 + (size_t)N_TOK * 4;

  unsigned char* Wq = (unsigned char*)(ws + OFF_W);
  unsigned char* h1q = (unsigned char*)(ws + OFF_H1);
  unsigned char* h2q = (unsigned char*)(ws + OFF_H2);
  float* pm1 = (float*)(ws + OFF_P + 0 * PSZ);
  float* pz1 = (float*)(ws + OFF_P + 1 * PSZ);
  float* pt = (float*)(ws + OFF_P + 2 * PSZ);
  float* pi1 = (float*)(ws + OFF_P + 3 * PSZ);
  float* pm2 = (float*)(ws + OFF_P + 4 * PSZ);
  float* pz2 = (float*)(ws + OFF_P + 5 * PSZ);
  float* pi2 = (float*)(ws + OFF_P + 6 * PSZ);
  float* tl1 = (float*)(ws + OFF_TL1);
  float* tl2 = (float*)(ws + OFF_TL2);
  float* tout = (float*)(ws + OFF_TOUT);

  // 1) fp8 quantization: W scaled by 64 (values ~N(0,0.02) -> ~N(0,1.28)),
  //    h unscaled (~N(0,1)); logits recovered via *1/64 in fused_gemm epilogue.
  {
    long n16w = (long)V_DIM * D_DIM / 16;  // 4,096,000
    cvt_f32_fp8<<<(n16w + 255) / 256, 256, 0, stream>>>(W, Wq, W_SCALE, n16w);
    long n16h = (long)N_TOK * D_DIM / 16;  // 524,288
    cvt_f32_fp8<<<(n16h + 255) / 256, 256, 0, stream>>>(h1, h1q, 1.0f, n16h);
    cvt_f32_fp8<<<(n16h + 255) / 256, 256, 0, stream>>>(h2, h2q, 1.0f, n16h);
  }
  // 2) target logits (fp32 exact)
  tgt_dot<<<N_TOK / 4, 256, 0, stream>>>(h1, h2, W, tgt, tl1, tl2);
  // 3) fused dual-GEMM (fp8 K=128) + tile partials
  {
    dim3 grid(NMT, NVT);
    fused_gemm<<<grid, 256, 0, stream>>>(h1q, h2q, Wq, pm1, pz1, pt, pi1, pm2, pz2, pi2);
  }
  // 4) per-token combine, 5) scalars
  token_combine<<<N_TOK / 256, 256, 0, stream>>>(pm1, pz1, pt, pi1, pm2, pz2, pi2, tl1, tl2, tgt, tout);
  finalize<<<1, 256, 0, stream>>>(tout, out);
}